// Round 5
// baseline (161.409 us; speedup 1.0000x reference)
//
#include <hip/hip_runtime.h>
#include <hip/hip_fp16.h>

#define IN_CH 256
#define OUT_CH 8

typedef float f32x4 __attribute__((ext_vector_type(4)));

__device__ __forceinline__ unsigned pack2h(float a, float b) {
    __half2 h = __floats2half2_rn(a, b);
    return *(unsigned*)&h;
}

// ---------------------------------------------------------------------------
// Projection v4: P1 = X @ W1^T, P2 = X @ W2^T -> packed f16 tables.
// Block = 4 waves, owns 64 nodes. Wave w computes k-quarter w (64 floats),
// in 2 chunks of 32: coalesced global->LDS transpose, lane pulls its node's
// 32 floats to VGPRs, W via wave-uniform scalar loads (readfirstlane keeps
// the quarter index provably uniform -> s_load, SGPR operands on the FMAs).
// Cross-wave reduce through LDS (buffer reused), packed f16 uint2 stores.
// ---------------------------------------------------------------------------
__global__ __launch_bounds__(256) void proj_kernel(
    const float* __restrict__ X,
    const float* __restrict__ W1,
    const float* __restrict__ W2,
    uint2* __restrict__ P1v,        // [n][2] -> 16 B/node packed 8xf16
    uint2* __restrict__ P2v,
    int n)
{
    __shared__ float Xs[4][64][36];     // 36.9 KB; stride 36 floats = 144 B

    const int tid     = threadIdx.x;
    const int wave    = tid >> 6;
    const int lane    = tid & 63;
    const int quarter = __builtin_amdgcn_readfirstlane(wave);  // SGPR-uniform
    const int base    = blockIdx.x * 64;
    const bool full   = (base + 64 <= n);

    float acc[16];                      // [0..7]=table1, [8..15]=table2
    #pragma unroll
    for (int k = 0; k < 16; ++k) acc[k] = 0.f;

    const float4* W1v = (const float4*)W1;   // [8][64] float4
    const float4* W2v = (const float4*)W2;

    #pragma unroll
    for (int ch = 0; ch < 2; ++ch) {
        // stage 64 rows x 32 floats of this wave's k-quarter (coalesced 128-B
        // segments: lanes 0-7 cover one row's 32 floats)
        #pragma unroll
        for (int j = 0; j < 8; ++j) {
            const int idx = lane + 64 * j;       // 0..511
            const int row = idx >> 3;
            const int q   = idx & 7;
            float4 v = make_float4(0.f, 0.f, 0.f, 0.f);
            if (full || base + row < n)
                v = *(const float4*)(X + (size_t)(base + row) * IN_CH
                                       + quarter * 64 + ch * 32 + q * 4);
            *(float4*)&Xs[wave][row][q * 4] = v;
        }
        // same-wave LDS write->read: compiler inserts lgkmcnt wait

        float4 xq[8];
        #pragma unroll
        for (int q = 0; q < 8; ++q)
            xq[q] = *(const float4*)&Xs[wave][lane][q * 4];

        #pragma unroll
        for (int o = 0; o < OUT_CH; ++o) {
            float s1 = 0.f, s2 = 0.f;
            #pragma unroll
            for (int q = 0; q < 8; ++q) {
                float4 w1 = W1v[o * 64 + quarter * 16 + ch * 8 + q];  // s_load
                float4 w2 = W2v[o * 64 + quarter * 16 + ch * 8 + q];
                float4 x  = xq[q];
                s1 += x.x * w1.x + x.y * w1.y + x.z * w1.z + x.w * w1.w;
                s2 += x.x * w2.x + x.y * w2.y + x.z * w2.z + x.w * w2.w;
            }
            acc[o]     += s1;
            acc[8 + o] += s2;
        }
    }

    // ---- cross-wave reduction (4 partial quarters per node) ----
    __syncthreads();                      // everyone done reading Xs
    float* Pr = &Xs[0][0][0];             // reuse as [4][64][17] partials
    #pragma unroll
    for (int k = 0; k < 16; ++k)
        Pr[(wave * 64 + lane) * 17 + k] = acc[k];
    __syncthreads();

    const int node  = tid >> 2;           // 0..63
    const int g     = tid & 3;            // acc group of 4
    const int gnode = base + node;
    if (gnode < n) {
        float r0 = 0.f, r1 = 0.f, r2 = 0.f, r3 = 0.f;
        #pragma unroll
        for (int w = 0; w < 4; ++w) {
            const float* p = &Pr[(w * 64 + node) * 17 + g * 4];
            r0 += p[0]; r1 += p[1]; r2 += p[2]; r3 += p[3];
        }
        uint2 val;
        val.x = pack2h(r0, r1);
        val.y = pack2h(r2, r3);
        uint2* dst = (g < 2) ? (P1v + (size_t)gnode * 2 + g)
                             : (P2v + (size_t)gnode * 2 + (g - 2));
        *dst = val;
    }
}

// ---------------------------------------------------------------------------
// Gather v4: out[e] = toF32(T1[e0[e]]) + toF32(T2[e1[e]])
// 4 edges per thread (strided by 256 within a 1024-edge block chunk so every
// load/store instruction is lane-consecutive) -> 4 independent
// index->table->store chains for latency hiding. Tables L2-resident;
// index loads + output stores nontemporal.
// ---------------------------------------------------------------------------
__device__ __forceinline__ void addh8(const uint4 a, const uint4 b,
                                      f32x4& r0, f32x4& r1) {
    const __half2* ah = (const __half2*)&a;
    const __half2* bh = (const __half2*)&b;
    float2 s0 = __half22float2(ah[0]);
    float2 s1 = __half22float2(ah[1]);
    float2 s2 = __half22float2(ah[2]);
    float2 s3 = __half22float2(ah[3]);
    float2 t0 = __half22float2(bh[0]);
    float2 t1 = __half22float2(bh[1]);
    float2 t2 = __half22float2(bh[2]);
    float2 t3 = __half22float2(bh[3]);
    r0 = (f32x4){ s0.x + t0.x, s0.y + t0.y, s1.x + t1.x, s1.y + t1.y };
    r1 = (f32x4){ s2.x + t2.x, s2.y + t2.y, s3.x + t3.x, s3.y + t3.y };
}

__global__ __launch_bounds__(256) void gather_kernel(
    const int* __restrict__ e0,
    const int* __restrict__ e1,
    const uint4* __restrict__ T1,
    const uint4* __restrict__ T2,
    f32x4* __restrict__ outv,
    int E, int n)
{
    const int tid  = threadIdx.x;
    const int base = blockIdx.x * 1024;
    const unsigned nmax = (unsigned)(n - 1);

    if (base + 1024 <= E) {
        unsigned i0[4], i1[4];
        #pragma unroll
        for (int k = 0; k < 4; ++k) {
            const int ek = base + k * 256 + tid;
            i0[k] = (unsigned)__builtin_nontemporal_load(e0 + ek);
            i1[k] = (unsigned)__builtin_nontemporal_load(e1 + ek);
        }
        uint4 a[4], b[4];
        #pragma unroll
        for (int k = 0; k < 4; ++k) {
            a[k] = T1[i0[k] > nmax ? nmax : i0[k]];
            b[k] = T2[i1[k] > nmax ? nmax : i1[k]];
        }
        #pragma unroll
        for (int k = 0; k < 4; ++k) {
            f32x4 r0, r1;
            addh8(a[k], b[k], r0, r1);
            const size_t oi = 2u * (size_t)(base + k * 256 + tid);
            __builtin_nontemporal_store(r0, outv + oi);
            __builtin_nontemporal_store(r1, outv + oi + 1);
        }
    } else {
        for (int k = 0; k < 4; ++k) {
            const int ek = base + k * 256 + tid;
            if (ek >= E) break;
            unsigned i0 = (unsigned)__builtin_nontemporal_load(e0 + ek);
            unsigned i1 = (unsigned)__builtin_nontemporal_load(e1 + ek);
            uint4 a = T1[i0 > nmax ? nmax : i0];
            uint4 b = T2[i1 > nmax ? nmax : i1];
            f32x4 r0, r1;
            addh8(a, b, r0, r1);
            const size_t oi = 2u * (size_t)ek;
            __builtin_nontemporal_store(r0, outv + oi);
            __builtin_nontemporal_store(r1, outv + oi + 1);
        }
    }
}

extern "C" void kernel_launch(void* const* d_in, const int* in_sizes, int n_in,
                              void* d_out, int out_size, void* d_ws, size_t ws_size,
                              hipStream_t stream) {
    const float* X    = (const float*)d_in[0];
    const int*   eidx = (const int*)d_in[1];
    const float* W1   = (const float*)d_in[2];
    const float* W2   = (const float*)d_in[3];

    const int n = in_sizes[0] / IN_CH;   // 100000
    const int E = in_sizes[1] / 2;       // 6400000

    uint2* P1v = (uint2*)d_ws;                        // [n] x 16 B = 1.6 MB
    uint2* P2v = P1v + (size_t)n * 2;                 // [n] x 16 B = 1.6 MB

    const int proj_blocks = (n + 63) / 64;            // 1563
    proj_kernel<<<proj_blocks, 256, 0, stream>>>(X, W1, W2, P1v, P2v, n);

    const int gather_blocks = (E + 1023) / 1024;      // 6250
    gather_kernel<<<gather_blocks, 256, 0, stream>>>(
        eidx, eidx + E, (const uint4*)P1v, (const uint4*)P2v,
        (f32x4*)d_out, E, n);
}

// Round 6
// 135.636 us; speedup vs baseline: 1.1900x; 1.1900x over previous
//
#include <hip/hip_runtime.h>
#include <hip/hip_fp16.h>

#define IN_CH 256
#define OUT_CH 8
#define RB 4   // rows in flight per wave iteration

typedef float f32x4 __attribute__((ext_vector_type(4)));

__device__ __forceinline__ unsigned pack2h(float a, float b) {
    __half2 h = __floats2half2_rn(a, b);
    return *(unsigned*)&h;
}

// ---------------------------------------------------------------------------
// Projection v6: one WAVE per row. No LDS, no barriers, no scalar W loads.
//  - row load: one global_load_dwordx4 = the full 1KB row, lane l -> floats
//    [4l..4l+3]  (perfectly coalesced, the m13-proven pattern)
//  - W in VGPRs: lane's slice W[o][4l..4l+3] for 16 outputs = 64 VGPRs,
//    loaded once per wave (L2-broadcast)
//  - per row: 64 FMA -> butterfly fold (masks 32,16,8,4 halve the live
//    accumulator set and split outputs across lanes; then ^1, ^2 plain
//    adds) -> lane group g=(lane>>2)&15 owns output g
//  - store: 16 active lanes write 2B each -> two 16B segments per row
// ---------------------------------------------------------------------------
__global__ __launch_bounds__(256) void proj_kernel(
    const float* __restrict__ X,
    const float4* __restrict__ W1v,   // [8][64] float4
    const float4* __restrict__ W2v,
    __half* __restrict__ P1h,         // [n][8] f16
    __half* __restrict__ P2h,
    int n, int nwaves)
{
    const int lane  = threadIdx.x & 63;
    const int gwave = (blockIdx.x * 256 + threadIdx.x) >> 6;

    // per-lane W slice, resident in VGPRs for the whole kernel
    float4 w[16];
    #pragma unroll
    for (int o = 0; o < 8; ++o) {
        w[o]     = W1v[o * 64 + lane];
        w[8 + o] = W2v[o * 64 + lane];
    }

    const int g      = (lane >> 2) & 15;          // output this lane group owns
    const bool owner = (lane & 3) == 0;

    for (int r0 = gwave * RB; r0 < n; r0 += nwaves * RB) {
        // ---- issue RB independent row loads (1KB contiguous each) ----
        float4 x[RB];
        #pragma unroll
        for (int b = 0; b < RB; ++b) {
            const int r = r0 + b;
            if (r < n)
                x[b] = *(const float4*)(X + (size_t)r * IN_CH + lane * 4);
        }

        #pragma unroll
        for (int b = 0; b < RB; ++b) {
            const int r = r0 + b;
            if (r >= n) break;

            // ---- 16 partial dots (4 FMA each) ----
            float acc[16];
            #pragma unroll
            for (int o = 0; o < 16; ++o) {
                const float4 ww = w[o];
                acc[o] = x[b].x * ww.x + x[b].y * ww.y
                       + x[b].z * ww.z + x[b].w * ww.w;
            }

            // ---- fold ^32: 16 -> 8 live accs (o<8 on lane bit5==0) ----
            #pragma unroll
            for (int j = 0; j < 8; ++j) {
                float give = (lane & 32) ? acc[j] : acc[j + 8];
                float keep = (lane & 32) ? acc[j + 8] : acc[j];
                acc[j] = keep + __shfl_xor(give, 32, 64);
            }
            // ---- fold ^16: 8 -> 4 ----
            #pragma unroll
            for (int j = 0; j < 4; ++j) {
                float give = (lane & 16) ? acc[j] : acc[j + 4];
                float keep = (lane & 16) ? acc[j + 4] : acc[j];
                acc[j] = keep + __shfl_xor(give, 16, 64);
            }
            // ---- fold ^8: 4 -> 2 ----
            #pragma unroll
            for (int j = 0; j < 2; ++j) {
                float give = (lane & 8) ? acc[j] : acc[j + 2];
                float keep = (lane & 8) ? acc[j + 2] : acc[j];
                acc[j] = keep + __shfl_xor(give, 8, 64);
            }
            // ---- fold ^4: 2 -> 1 ----
            {
                float give = (lane & 4) ? acc[0] : acc[1];
                float keep = (lane & 4) ? acc[1] : acc[0];
                acc[0] = keep + __shfl_xor(give, 4, 64);
            }
            // ---- finish across the mod-4 lane classes ----
            float a = acc[0];
            a += __shfl_xor(a, 1, 64);
            a += __shfl_xor(a, 2, 64);
            // lane group g now holds the full dot for output g

            if (owner) {
                __half h = __float2half(a);
                __half* dst = (g < 8)
                    ? (P1h + (size_t)r * OUT_CH + g)
                    : (P2h + (size_t)r * OUT_CH + (g - 8));
                *dst = h;
            }
        }
    }
}

// ---------------------------------------------------------------------------
// Gather (unchanged): out[e] = toF32(T1[e0[e]]) + toF32(T2[e1[e]])
// 4 edges/thread, lane-consecutive accesses, tables L2-resident, nt streams.
// ---------------------------------------------------------------------------
__device__ __forceinline__ void addh8(const uint4 a, const uint4 b,
                                      f32x4& r0, f32x4& r1) {
    const __half2* ah = (const __half2*)&a;
    const __half2* bh = (const __half2*)&b;
    float2 s0 = __half22float2(ah[0]);
    float2 s1 = __half22float2(ah[1]);
    float2 s2 = __half22float2(ah[2]);
    float2 s3 = __half22float2(ah[3]);
    float2 t0 = __half22float2(bh[0]);
    float2 t1 = __half22float2(bh[1]);
    float2 t2 = __half22float2(bh[2]);
    float2 t3 = __half22float2(bh[3]);
    r0 = (f32x4){ s0.x + t0.x, s0.y + t0.y, s1.x + t1.x, s1.y + t1.y };
    r1 = (f32x4){ s2.x + t2.x, s2.y + t2.y, s3.x + t3.x, s3.y + t3.y };
}

__global__ __launch_bounds__(256) void gather_kernel(
    const int* __restrict__ e0,
    const int* __restrict__ e1,
    const uint4* __restrict__ T1,
    const uint4* __restrict__ T2,
    f32x4* __restrict__ outv,
    int E, int n)
{
    const int tid  = threadIdx.x;
    const int base = blockIdx.x * 1024;
    const unsigned nmax = (unsigned)(n - 1);

    if (base + 1024 <= E) {
        unsigned i0[4], i1[4];
        #pragma unroll
        for (int k = 0; k < 4; ++k) {
            const int ek = base + k * 256 + tid;
            i0[k] = (unsigned)__builtin_nontemporal_load(e0 + ek);
            i1[k] = (unsigned)__builtin_nontemporal_load(e1 + ek);
        }
        uint4 a[4], b[4];
        #pragma unroll
        for (int k = 0; k < 4; ++k) {
            a[k] = T1[i0[k] > nmax ? nmax : i0[k]];
            b[k] = T2[i1[k] > nmax ? nmax : i1[k]];
        }
        #pragma unroll
        for (int k = 0; k < 4; ++k) {
            f32x4 r0, r1;
            addh8(a[k], b[k], r0, r1);
            const size_t oi = 2u * (size_t)(base + k * 256 + tid);
            __builtin_nontemporal_store(r0, outv + oi);
            __builtin_nontemporal_store(r1, outv + oi + 1);
        }
    } else {
        for (int k = 0; k < 4; ++k) {
            const int ek = base + k * 256 + tid;
            if (ek >= E) break;
            unsigned i0 = (unsigned)__builtin_nontemporal_load(e0 + ek);
            unsigned i1 = (unsigned)__builtin_nontemporal_load(e1 + ek);
            uint4 a = T1[i0 > nmax ? nmax : i0];
            uint4 b = T2[i1 > nmax ? nmax : i1];
            f32x4 r0, r1;
            addh8(a, b, r0, r1);
            const size_t oi = 2u * (size_t)ek;
            __builtin_nontemporal_store(r0, outv + oi);
            __builtin_nontemporal_store(r1, outv + oi + 1);
        }
    }
}

extern "C" void kernel_launch(void* const* d_in, const int* in_sizes, int n_in,
                              void* d_out, int out_size, void* d_ws, size_t ws_size,
                              hipStream_t stream) {
    const float* X    = (const float*)d_in[0];
    const int*   eidx = (const int*)d_in[1];
    const float* W1   = (const float*)d_in[2];
    const float* W2   = (const float*)d_in[3];

    const int n = in_sizes[0] / IN_CH;   // 100000
    const int E = in_sizes[1] / 2;       // 6400000

    __half* P1h = (__half*)d_ws;                    // [n][8] f16 = 1.6 MB
    __half* P2h = P1h + (size_t)n * OUT_CH;         // [n][8] f16 = 1.6 MB

    const int proj_blocks = 1024;                   // 4096 waves, ~6 batches ea
    const int nwaves = proj_blocks * 4;
    proj_kernel<<<proj_blocks, 256, 0, stream>>>(
        X, (const float4*)W1, (const float4*)W2, P1h, P2h, n, nwaves);

    const int gather_blocks = (E + 1023) / 1024;    // 6250
    gather_kernel<<<gather_blocks, 256, 0, stream>>>(
        eidx, eidx + E, (const uint4*)P1h, (const uint4*)P2h,
        (f32x4*)d_out, E, n);
}